// Round 6
// baseline (799.745 us; speedup 1.0000x reference)
//
#include <hip/hip_runtime.h>

// v10b: verbatim resubmit of v10 (round-5 bench died in infra: "container
// failed twice" — same transient class as round 3, whose identical resubmit
// then passed). Asm re-audited vs verified C threefry: rotations, injections
// (KS2=0x1BD11BF0), round-1 a=0 special case, bit31 drop sense all match.
//
// v10: monolith (v6 structure, 715us verified) + inline-asm threefry.
// Round-4 evidence: maskgen at VGPR=4 / VALUBusy 96% / 0 conflicts still took
// 497us for 2^23 words => sustained clock under full-VALU load ~1.3 GHz (not
// 2.4). At that clock v6's 715us is near the VALU floor WITH overlap; the
// kernel split (797us) loses the overlap of threefry with MFMA/mem phases.
// Lever: pin threefry at its 70-instr/element floor with inline asm (immune
// to the allocator squeezes that made v7/v8 fat at VGPR 40/56). Each asm
// block computes TWO interleaved chains (ILP=2) so 3-4 waves/SIMD covers the
// 4-cyc VALU dep latency. No reg-prefetch (v6 staging; occupancy hides it).

#define S_LEN 2048
#define D_DIM 64
#define KT    32
#define QT    16
#define NWAVE 4
#define KSTR  72   // K row stride (shorts): b128 frag reads 2-way (free)
#define VROW  66   // V row-major stride (shorts): scalar u16 reads conflict-free
#define PSTR  40   // P row stride (shorts): b128 reads conflict-optimal

typedef short  short8  __attribute__((ext_vector_type(8)));
typedef float  floatx4 __attribute__((ext_vector_type(4)));

// Paired threefry2x32 (key (0,42), ctr (0,i)), partitionable form:
// w = x0 ^ x1; drop(i) <=> bit31(w) == 1.  Two independent chains
// interleaved in one asm block: %0/%1 = b/a of chain0, %2/%3 = b/a of
// chain1, %4/%5 = i0/i1. Rotation r -> alignbit shift 32-r.
// Schedule (== verified C version): G1/G3/G5 rot 13,15,26,6; G2/G4 rot
// 17,29,16,24; injections a+=42|KS2, b+=KS2+1,2,45,KS2+4,5 (KS2=0x1BD11BF0).
#define TF_R2(sh) \
  "v_add_u32 %1, %1, %0\n\t" \
  "v_add_u32 %3, %3, %2\n\t" \
  "v_alignbit_b32 %0, %0, %0, " #sh "\n\t" \
  "v_alignbit_b32 %2, %2, %2, " #sh "\n\t" \
  "v_xor_b32 %0, %0, %1\n\t" \
  "v_xor_b32 %2, %2, %3\n\t"

__device__ __forceinline__ void tf2(unsigned i0, unsigned i1,
                                    unsigned& w0, unsigned& w1) {
  unsigned a0, a1;
  asm(
    // init: b = i + 42  (ctr1 + key1)
    "v_add_u32 %0, 42, %4\n\t"
    "v_add_u32 %2, 42, %5\n\t"
    // round 1 (a starts at 0): a = b; b = rotl(b,13) ^ a
    "v_mov_b32 %1, %0\n\t"
    "v_mov_b32 %3, %2\n\t"
    "v_alignbit_b32 %0, %0, %0, 19\n\t"
    "v_alignbit_b32 %2, %2, %2, 19\n\t"
    "v_xor_b32 %0, %0, %1\n\t"
    "v_xor_b32 %2, %2, %3\n\t"
    TF_R2(17) TF_R2(6) TF_R2(26)
    // inject 1: a += 42; b += KS2+1
    "v_add_u32 %1, 42, %1\n\t"
    "v_add_u32 %3, 42, %3\n\t"
    "v_add_u32 %0, 0x1bd11bf1, %0\n\t"
    "v_add_u32 %2, 0x1bd11bf1, %2\n\t"
    TF_R2(15) TF_R2(3) TF_R2(16) TF_R2(8)
    // inject 2: a += KS2; b += 2
    "v_add_u32 %1, 0x1bd11bf0, %1\n\t"
    "v_add_u32 %3, 0x1bd11bf0, %3\n\t"
    "v_add_u32 %0, 2, %0\n\t"
    "v_add_u32 %2, 2, %2\n\t"
    TF_R2(19) TF_R2(17) TF_R2(6) TF_R2(26)
    // inject 3: b += 45  (a += key0 = 0 elided)
    "v_add_u32 %0, 45, %0\n\t"
    "v_add_u32 %2, 45, %2\n\t"
    TF_R2(15) TF_R2(3) TF_R2(16) TF_R2(8)
    // inject 4: a += 42; b += KS2+4
    "v_add_u32 %1, 42, %1\n\t"
    "v_add_u32 %3, 42, %3\n\t"
    "v_add_u32 %0, 0x1bd11bf4, %0\n\t"
    "v_add_u32 %2, 0x1bd11bf4, %2\n\t"
    TF_R2(19) TF_R2(17) TF_R2(6) TF_R2(26)
    // inject 5: a += KS2; b += 5
    "v_add_u32 %1, 0x1bd11bf0, %1\n\t"
    "v_add_u32 %3, 0x1bd11bf0, %3\n\t"
    "v_add_u32 %0, 5, %0\n\t"
    "v_add_u32 %2, 5, %2\n\t"
    // w = a ^ b
    "v_xor_b32 %0, %0, %1\n\t"
    "v_xor_b32 %2, %2, %3"
    : "=&v"(w0), "=&v"(a0), "=&v"(w1), "=&v"(a1)
    : "v"(i0), "v"(i1));
}

__device__ __forceinline__ void split_bf16(float x, unsigned short& h, unsigned short& l) {
  unsigned u = __float_as_uint(x);
  h = (unsigned short)(u >> 16);
  float r = x - __uint_as_float(u & 0xFFFF0000u);
  l = (unsigned short)(__float_as_uint(r) >> 16);
}

#define MFMA(a, b, c) __builtin_amdgcn_mfma_f32_16x16x32_bf16((a), (b), (c), 0, 0, 0)

__global__ __launch_bounds__(256, 6) void attn_fused_v10(
    const float* __restrict__ Qg, const float* __restrict__ Kg,
    const float* __restrict__ Vg, float* __restrict__ Og) {

  __shared__ __attribute__((aligned(16))) unsigned short Kh[KT * KSTR];
  __shared__ __attribute__((aligned(16))) unsigned short Kl[KT * KSTR];
  __shared__ __attribute__((aligned(16))) unsigned short Vs[KT * VROW];
  __shared__ __attribute__((aligned(16))) unsigned short Ph[NWAVE][QT * PSTR];

  const int tid  = threadIdx.x;
  const int wave = tid >> 6;
  const int lane = tid & 63;
  const int m16  = lane & 15;
  const int quad = lane >> 4;

  const int bh    = blockIdx.x >> 5;   // 64 (b,h) heads
  const int qtile = blockIdx.x & 31;   // 32 q-tiles of 64 rows
  const int q0    = qtile * (QT * NWAVE) + wave * QT;
  const size_t head_off = (size_t)bh * S_LEN * D_DIM;

  // Q A-fragments (hi/lo split): A[m=m16][k = kc*32 + quad*8 + j]
  short8 qh[2], ql[2];
#pragma unroll
  for (int kc = 0; kc < 2; ++kc) {
    const float* qp = Qg + head_off + (size_t)(q0 + m16) * D_DIM + kc * 32 + quad * 8;
    floatx4 f0 = *(const floatx4*)qp;
    floatx4 f1 = *(const floatx4*)(qp + 4);
#pragma unroll
    for (int e = 0; e < 4; ++e) {
      unsigned short h, l;
      split_bf16(f0[e], h, l);
      qh[kc][e] = (short)h;  ql[kc][e] = (short)l;
      split_bf16(f1[e], h, l);
      qh[kc][4 + e] = (short)h;  ql[kc][4 + e] = (short)l;
    }
  }

  floatx4 o_acc[4];
#pragma unroll
  for (int n = 0; n < 4; ++n) o_acc[n] = (floatx4){0.f, 0.f, 0.f, 0.f};
  float lsum[4];
#pragma unroll
  for (int r = 0; r < 4; ++r) lsum[r] = 0.f;

  // flat mask index: i = (bh*2048 + q)*2048 + k; q = q0+quad*4+r, k = kb+nb*16+m16
  const unsigned ibase0 =
      ((unsigned)(bh * S_LEN + q0 + quad * 4)) * (unsigned)S_LEN + (unsigned)m16;

  for (int kb = 0; kb < S_LEN; kb += KT) {
    __syncthreads();   // prior iteration's Kh/Kl/Vs reads complete

    // ---- stage K (hi+lo) and V (hi only, row-major) into LDS
    for (int f = tid; f < KT * (D_DIM / 4); f += 256) {
      int row = f >> 4;
      int c4  = (f & 15) << 2;
      size_t goff = head_off + (size_t)(kb + row) * D_DIM + c4;
      floatx4 kv = *(const floatx4*)(Kg + goff);
      floatx4 vv = *(const floatx4*)(Vg + goff);
      unsigned short h0, h1, h2, h3, l0, l1, l2, l3;
      split_bf16(kv[0], h0, l0); split_bf16(kv[1], h1, l1);
      split_bf16(kv[2], h2, l2); split_bf16(kv[3], h3, l3);
      int kidx = row * KSTR + c4;
      *(unsigned*)&Kh[kidx]     = (unsigned)h0 | ((unsigned)h1 << 16);
      *(unsigned*)&Kh[kidx + 2] = (unsigned)h2 | ((unsigned)h3 << 16);
      *(unsigned*)&Kl[kidx]     = (unsigned)l0 | ((unsigned)l1 << 16);
      *(unsigned*)&Kl[kidx + 2] = (unsigned)l2 | ((unsigned)l3 << 16);
      unsigned v01 = (__float_as_uint(vv[0]) >> 16) |
                     (__float_as_uint(vv[1]) & 0xFFFF0000u);
      unsigned v23 = (__float_as_uint(vv[2]) >> 16) |
                     (__float_as_uint(vv[3]) & 0xFFFF0000u);
      int vidx = row * VROW + c4;
      *(unsigned*)&Vs[vidx]     = v01;
      *(unsigned*)&Vs[vidx + 2] = v23;
    }
    __syncthreads();

    // ---- S = Q K^T (split-bf16 3-term: hh + hl + lh)
    floatx4 sc[2];
#pragma unroll
    for (int nb = 0; nb < 2; ++nb) {
      floatx4 acc = (floatx4){0.f, 0.f, 0.f, 0.f};
#pragma unroll
      for (int kc = 0; kc < 2; ++kc) {
        int bidx = (nb * 16 + m16) * KSTR + kc * 32 + quad * 8;
        short8 kbh = *(const short8*)&Kh[bidx];
        short8 kbl = *(const short8*)&Kl[bidx];
        acc = MFMA(qh[kc], kbh, acc);
        acc = MFMA(qh[kc], kbl, acc);
        acc = MFMA(ql[kc], kbh, acc);
      }
      sc[nb] = acc;
    }

    // ---- p = exp(s) (|s| <~ 50: no overflow), per-lane l partial,
    //      asm-threefry mask (paired chains), P(hi bf16, masked) -> LDS
#pragma unroll
    for (int r = 0; r < 4; ++r) {
      unsigned i0 = ibase0 + (unsigned)kb + (unsigned)(r * S_LEN);
      unsigned w0, w1;
      tf2(i0, i0 + 16u, w0, w1);   // nb=0 (k=..+m16), nb=1 (k=..+16+m16)
#pragma unroll
      for (int nb = 0; nb < 2; ++nb) {
        float pe = __expf(sc[nb][r]);
        lsum[r] += pe;
        unsigned hbits = __float_as_uint(pe) >> 16;
        unsigned w = nb ? w1 : w0;
        hbits = ((int)w < 0) ? 0u : hbits;   // bit31(w)=1 -> drop
        Ph[wave][(quad * 4 + r) * PSTR + nb * 16 + m16] = (unsigned short)hbits;
      }
    }
    // Ph is wave-private; same-wave LDS RAW handled by lgkmcnt.

    // ---- O += P V  (P hi x V hi); V B-frag via conflict-free scalar u16
    short8 pa = *(const short8*)&Ph[wave][m16 * PSTR + quad * 8];
#pragma unroll
    for (int n = 0; n < 4; ++n) {
      short8 vb;
#pragma unroll
      for (int j = 0; j < 8; ++j)
        vb[j] = (short)Vs[(quad * 8 + j) * VROW + n * 16 + m16];
      o_acc[n] = MFMA(pa, vb, o_acc[n]);
    }
  }

  // ---- final l reduction over the 16 m16 lanes
#pragma unroll
  for (int off = 8; off >= 1; off >>= 1)
#pragma unroll
    for (int r = 0; r < 4; ++r)
      lsum[r] += __shfl_xor(lsum[r], off, 64);

  // ---- epilogue: out = O * (2 / l)   (2 = 1/(1-p) dropout scale)
#pragma unroll
  for (int r = 0; r < 4; ++r) {
    float scale = 2.0f / lsum[r];
#pragma unroll
    for (int n = 0; n < 4; ++n) {
      Og[head_off + (size_t)(q0 + quad * 4 + r) * D_DIM + n * 16 + m16] =
          o_acc[n][r] * scale;
    }
  }
}

extern "C" void kernel_launch(void* const* d_in, const int* in_sizes, int n_in,
                              void* d_out, int out_size, void* d_ws, size_t ws_size,
                              hipStream_t stream) {
  (void)in_sizes; (void)n_in; (void)out_size; (void)d_ws; (void)ws_size;
  const float* Q = (const float*)d_in[0];
  const float* K = (const float*)d_in[1];
  const float* V = (const float*)d_in[2];
  float* O = (float*)d_out;
  hipLaunchKernelGGL(attn_fused_v10, dim3(2048), dim3(256), 0, stream, Q, K, V, O);
}

// Round 7
// 766.927 us; speedup vs baseline: 1.0428x; 1.0428x over previous
//
#include <hip/hip_runtime.h>

// v11: v10 monolith + K-split prep kernel (tier-1, fits the PROVEN >=32MiB ws).
// Round-6 decomposition: threefry floor = 497us (maskgen: VGPR=4, 96% busy,
// instruction-exact) at the sustained ~1.2GHz VALU clock; v10 = 770 = 497 +
// ~270 of non-threefry work. Largest removable piece: K hi/lo split staging
// (~100 VALU/thread/iter, recomputed by all 32 blocks per head). prep_kv
// splits K once -> KH/KL bf16 arrays in ws (exactly 32MiB, same size check
// v9's mask path already passed); attn K-staging becomes short8 copy +
// ds_write_b128. LDS accesses rewritten as const-base + compile-time offsets
// so ds_read_u16/ds_write_b16 use the immediate-offset form (no per-iter
// address VALU). Threefry asm / mask / MFMA / epilogue identical to v10.

#define S_LEN 2048
#define D_DIM 64
#define KT    32
#define QT    16
#define NWAVE 4
#define KSTR  72   // K row stride (shorts): b128 frag reads 2-way (free)
#define VROW  66   // V row-major stride (shorts): scalar u16 reads conflict-free
#define PSTR  40   // P row stride (shorts): b128 reads conflict-optimal

typedef short  short8  __attribute__((ext_vector_type(8)));
typedef float  floatx4 __attribute__((ext_vector_type(4)));
typedef unsigned uint2v __attribute__((ext_vector_type(2)));

// Paired threefry2x32 (key (0,42), ctr (0,i)), partitionable form:
// w = x0 ^ x1; drop(i) <=> bit31(w) == 1. Two independent chains interleaved
// (ILP=2). Rotation r -> alignbit shift 32-r. Verified vs C version (v10).
#define TF_R2(sh) \
  "v_add_u32 %1, %1, %0\n\t" \
  "v_add_u32 %3, %3, %2\n\t" \
  "v_alignbit_b32 %0, %0, %0, " #sh "\n\t" \
  "v_alignbit_b32 %2, %2, %2, " #sh "\n\t" \
  "v_xor_b32 %0, %0, %1\n\t" \
  "v_xor_b32 %2, %2, %3\n\t"

__device__ __forceinline__ void tf2(unsigned i0, unsigned i1,
                                    unsigned& w0, unsigned& w1) {
  unsigned a0, a1;
  asm(
    "v_add_u32 %0, 42, %4\n\t"
    "v_add_u32 %2, 42, %5\n\t"
    "v_mov_b32 %1, %0\n\t"
    "v_mov_b32 %3, %2\n\t"
    "v_alignbit_b32 %0, %0, %0, 19\n\t"
    "v_alignbit_b32 %2, %2, %2, 19\n\t"
    "v_xor_b32 %0, %0, %1\n\t"
    "v_xor_b32 %2, %2, %3\n\t"
    TF_R2(17) TF_R2(6) TF_R2(26)
    "v_add_u32 %1, 42, %1\n\t"
    "v_add_u32 %3, 42, %3\n\t"
    "v_add_u32 %0, 0x1bd11bf1, %0\n\t"
    "v_add_u32 %2, 0x1bd11bf1, %2\n\t"
    TF_R2(15) TF_R2(3) TF_R2(16) TF_R2(8)
    "v_add_u32 %1, 0x1bd11bf0, %1\n\t"
    "v_add_u32 %3, 0x1bd11bf0, %3\n\t"
    "v_add_u32 %0, 2, %0\n\t"
    "v_add_u32 %2, 2, %2\n\t"
    TF_R2(19) TF_R2(17) TF_R2(6) TF_R2(26)
    "v_add_u32 %0, 45, %0\n\t"
    "v_add_u32 %2, 45, %2\n\t"
    TF_R2(15) TF_R2(3) TF_R2(16) TF_R2(8)
    "v_add_u32 %1, 42, %1\n\t"
    "v_add_u32 %3, 42, %3\n\t"
    "v_add_u32 %0, 0x1bd11bf4, %0\n\t"
    "v_add_u32 %2, 0x1bd11bf4, %2\n\t"
    TF_R2(19) TF_R2(17) TF_R2(6) TF_R2(26)
    "v_add_u32 %1, 0x1bd11bf0, %1\n\t"
    "v_add_u32 %3, 0x1bd11bf0, %3\n\t"
    "v_add_u32 %0, 5, %0\n\t"
    "v_add_u32 %2, 5, %2\n\t"
    "v_xor_b32 %0, %0, %1\n\t"
    "v_xor_b32 %2, %2, %3"
    : "=&v"(w0), "=&v"(a0), "=&v"(w1), "=&v"(a1)
    : "v"(i0), "v"(i1));
}

__device__ __forceinline__ void split_bf16(float x, unsigned short& h, unsigned short& l) {
  unsigned u = __float_as_uint(x);
  h = (unsigned short)(u >> 16);
  float r = x - __uint_as_float(u & 0xFFFF0000u);
  l = (unsigned short)(__float_as_uint(r) >> 16);
}

#define MFMA(a, b, c) __builtin_amdgcn_mfma_f32_16x16x32_bf16((a), (b), (c), 0, 0, 0)

// ---- prep: split K (f32) into bf16 hi/lo arrays, once. Memory-bound.
__global__ __launch_bounds__(256) void prep_kv(
    const float* __restrict__ Kg, unsigned short* __restrict__ KHg,
    unsigned short* __restrict__ KLg) {
  unsigned t  = blockIdx.x * 256u + threadIdx.x;
  unsigned i4 = t * 4u;                      // 4 elements/thread, 8.4M total
  floatx4 kv = *(const floatx4*)(Kg + i4);
  unsigned short h0, h1, h2, h3, l0, l1, l2, l3;
  split_bf16(kv[0], h0, l0); split_bf16(kv[1], h1, l1);
  split_bf16(kv[2], h2, l2); split_bf16(kv[3], h3, l3);
  uint2v hh, ll;
  hh[0] = (unsigned)h0 | ((unsigned)h1 << 16);
  hh[1] = (unsigned)h2 | ((unsigned)h3 << 16);
  ll[0] = (unsigned)l0 | ((unsigned)l1 << 16);
  ll[1] = (unsigned)l2 | ((unsigned)l3 << 16);
  *(uint2v*)(KHg + i4) = hh;
  *(uint2v*)(KLg + i4) = ll;
}

// ---- fused attention. PREPPED=true: K staged from pre-split bf16 arrays.
template <bool PREPPED>
__global__ __launch_bounds__(256, 6) void attn_v11(
    const float* __restrict__ Qg, const float* __restrict__ Kg,
    const float* __restrict__ Vg, float* __restrict__ Og,
    const unsigned short* __restrict__ KHg,
    const unsigned short* __restrict__ KLg) {

  __shared__ __attribute__((aligned(16))) unsigned short Kh[KT * KSTR];
  __shared__ __attribute__((aligned(16))) unsigned short Kl[KT * KSTR];
  __shared__ __attribute__((aligned(16))) unsigned short Vs[KT * VROW];
  __shared__ __attribute__((aligned(16))) unsigned short Ph[NWAVE][QT * PSTR];

  const int tid  = threadIdx.x;
  const int wave = tid >> 6;
  const int lane = tid & 63;
  const int m16  = lane & 15;
  const int quad = lane >> 4;

  const int bh    = blockIdx.x >> 5;   // 64 (b,h) heads
  const int qtile = blockIdx.x & 31;   // 32 q-tiles of 64 rows
  const int q0    = qtile * (QT * NWAVE) + wave * QT;
  const size_t head_off = (size_t)bh * S_LEN * D_DIM;

  // Q A-fragments (hi/lo split): A[m=m16][k = kc*32 + quad*8 + j]
  short8 qh[2], ql[2];
#pragma unroll
  for (int kc = 0; kc < 2; ++kc) {
    const float* qp = Qg + head_off + (size_t)(q0 + m16) * D_DIM + kc * 32 + quad * 8;
    floatx4 f0 = *(const floatx4*)qp;
    floatx4 f1 = *(const floatx4*)(qp + 4);
#pragma unroll
    for (int e = 0; e < 4; ++e) {
      unsigned short h, l;
      split_bf16(f0[e], h, l);
      qh[kc][e] = (short)h;  ql[kc][e] = (short)l;
      split_bf16(f1[e], h, l);
      qh[kc][4 + e] = (short)h;  ql[kc][4 + e] = (short)l;
    }
  }

  floatx4 o_acc[4];
#pragma unroll
  for (int n = 0; n < 4; ++n) o_acc[n] = (floatx4){0.f, 0.f, 0.f, 0.f};
  float lsum[4];
#pragma unroll
  for (int r = 0; r < 4; ++r) lsum[r] = 0.f;

  // flat mask index: i = (bh*2048 + q)*2048 + k; q = q0+quad*4+r, k = kb+nb*16+m16
  const unsigned ibase0 =
      ((unsigned)(bh * S_LEN + q0 + quad * 4)) * (unsigned)S_LEN + (unsigned)m16;

  // thread-constant LDS bases (compile-time offsets fold into ds imm fields)
  const unsigned short* kh_rd = &Kh[m16 * KSTR + quad * 8];
  const unsigned short* kl_rd = &Kl[m16 * KSTR + quad * 8];
  const unsigned short* v_rd  = &Vs[(quad * 8) * VROW + m16];
  unsigned short*       p_wr  = &Ph[wave][(quad * 4) * PSTR + m16];
  const unsigned short* p_rd  = &Ph[wave][m16 * PSTR + quad * 8];

  for (int kb = 0; kb < S_LEN; kb += KT) {
    __syncthreads();   // prior iteration's Kh/Kl/Vs reads complete

    // ---- stage K and V into LDS
    if constexpr (PREPPED) {
      // K: pure copy of pre-split bf16 (1 pass, 16B/thread/array)
      const int row = tid >> 3;           // 0..31
      const int c8  = (tid & 7) * 8;      // 0..56
      const size_t koff = head_off + (size_t)(kb + row) * D_DIM + c8;
      short8 kh8 = *(const short8*)(KHg + koff);
      short8 kl8 = *(const short8*)(KLg + koff);
      *(short8*)&Kh[row * KSTR + c8] = kh8;
      *(short8*)&Kl[row * KSTR + c8] = kl8;
      // V: hi-pack (cheap: 2 ops/u32)
      for (int f = tid; f < KT * (D_DIM / 4); f += 256) {
        int vrow = f >> 4;
        int c4   = (f & 15) << 2;
        floatx4 vv = *(const floatx4*)(Vg + head_off + (size_t)(kb + vrow) * D_DIM + c4);
        unsigned v01 = (__float_as_uint(vv[0]) >> 16) |
                       (__float_as_uint(vv[1]) & 0xFFFF0000u);
        unsigned v23 = (__float_as_uint(vv[2]) >> 16) |
                       (__float_as_uint(vv[3]) & 0xFFFF0000u);
        int vidx = vrow * VROW + c4;
        *(unsigned*)&Vs[vidx]     = v01;
        *(unsigned*)&Vs[vidx + 2] = v23;
      }
    } else {
      // fallback: v10 staging (split K in-kernel)
      for (int f = tid; f < KT * (D_DIM / 4); f += 256) {
        int row = f >> 4;
        int c4  = (f & 15) << 2;
        size_t goff = head_off + (size_t)(kb + row) * D_DIM + c4;
        floatx4 kv = *(const floatx4*)(Kg + goff);
        floatx4 vv = *(const floatx4*)(Vg + goff);
        unsigned short h0, h1, h2, h3, l0, l1, l2, l3;
        split_bf16(kv[0], h0, l0); split_bf16(kv[1], h1, l1);
        split_bf16(kv[2], h2, l2); split_bf16(kv[3], h3, l3);
        int kidx = row * KSTR + c4;
        *(unsigned*)&Kh[kidx]     = (unsigned)h0 | ((unsigned)h1 << 16);
        *(unsigned*)&Kh[kidx + 2] = (unsigned)h2 | ((unsigned)h3 << 16);
        *(unsigned*)&Kl[kidx]     = (unsigned)l0 | ((unsigned)l1 << 16);
        *(unsigned*)&Kl[kidx + 2] = (unsigned)l2 | ((unsigned)l3 << 16);
        unsigned v01 = (__float_as_uint(vv[0]) >> 16) |
                       (__float_as_uint(vv[1]) & 0xFFFF0000u);
        unsigned v23 = (__float_as_uint(vv[2]) >> 16) |
                       (__float_as_uint(vv[3]) & 0xFFFF0000u);
        int vidx = row * VROW + c4;
        *(unsigned*)&Vs[vidx]     = v01;
        *(unsigned*)&Vs[vidx + 2] = v23;
      }
    }
    __syncthreads();

    // ---- S = Q K^T (split-bf16 3-term: hh + hl + lh)
    floatx4 sc[2];
#pragma unroll
    for (int nb = 0; nb < 2; ++nb) {
      floatx4 acc = (floatx4){0.f, 0.f, 0.f, 0.f};
#pragma unroll
      for (int kc = 0; kc < 2; ++kc) {
        short8 kbh = *(const short8*)&kh_rd[nb * 16 * KSTR + kc * 32];
        short8 kbl = *(const short8*)&kl_rd[nb * 16 * KSTR + kc * 32];
        acc = MFMA(qh[kc], kbh, acc);
        acc = MFMA(qh[kc], kbl, acc);
        acc = MFMA(ql[kc], kbh, acc);
      }
      sc[nb] = acc;
    }

    // ---- p = exp(s), per-lane l partial, asm-threefry mask, P -> LDS
#pragma unroll
    for (int r = 0; r < 4; ++r) {
      unsigned i0 = ibase0 + (unsigned)kb + (unsigned)(r * S_LEN);
      unsigned w0, w1;
      tf2(i0, i0 + 16u, w0, w1);   // nb=0, nb=1
#pragma unroll
      for (int nb = 0; nb < 2; ++nb) {
        float pe = __expf(sc[nb][r]);
        lsum[r] += pe;
        unsigned hbits = __float_as_uint(pe) >> 16;
        unsigned w = nb ? w1 : w0;
        hbits = ((int)w < 0) ? 0u : hbits;   // bit31(w)=1 -> drop
        p_wr[r * PSTR + nb * 16] = (unsigned short)hbits;
      }
    }
    // Ph is wave-private; same-wave LDS RAW handled by lgkmcnt.

    // ---- O += P V  (const-base + imm-offset ds_read_u16, conflict-free)
    short8 pa = *(const short8*)p_rd;
#pragma unroll
    for (int n = 0; n < 4; ++n) {
      short8 vb;
#pragma unroll
      for (int j = 0; j < 8; ++j)
        vb[j] = (short)v_rd[j * VROW + n * 16];
      o_acc[n] = MFMA(pa, vb, o_acc[n]);
    }
  }

  // ---- final l reduction over the 16 m16 lanes
#pragma unroll
  for (int off = 8; off >= 1; off >>= 1)
#pragma unroll
    for (int r = 0; r < 4; ++r)
      lsum[r] += __shfl_xor(lsum[r], off, 64);

  // ---- epilogue: out = O * (2 / l)   (2 = 1/(1-p) dropout scale)
#pragma unroll
  for (int r = 0; r < 4; ++r) {
    float scale = 2.0f / lsum[r];
#pragma unroll
    for (int n = 0; n < 4; ++n) {
      Og[head_off + (size_t)(q0 + quad * 4 + r) * D_DIM + n * 16 + m16] =
          o_acc[n][r] * scale;
    }
  }
}

extern "C" void kernel_launch(void* const* d_in, const int* in_sizes, int n_in,
                              void* d_out, int out_size, void* d_ws, size_t ws_size,
                              hipStream_t stream) {
  (void)in_sizes; (void)n_in; (void)out_size;
  const float* Q = (const float*)d_in[0];
  const float* K = (const float*)d_in[1];
  const float* V = (const float*)d_in[2];
  float* O = (float*)d_out;

  const size_t KELTS = (size_t)64 * S_LEN * D_DIM;          // 8,388,608
  const size_t NEED  = 2 * KELTS * sizeof(unsigned short);  // 33,554,432 B
  if (d_ws != nullptr && ws_size >= NEED) {
    unsigned short* KH = (unsigned short*)d_ws;
    unsigned short* KL = KH + KELTS;
    hipLaunchKernelGGL(prep_kv, dim3((unsigned)(KELTS / 4 / 256)), dim3(256),
                       0, stream, K, KH, KL);
    hipLaunchKernelGGL((attn_v11<true>), dim3(2048), dim3(256), 0, stream,
                       Q, K, V, O, KH, KL);
  } else {
    hipLaunchKernelGGL((attn_v11<false>), dim3(2048), dim3(256), 0, stream,
                       Q, K, V, O, (const unsigned short*)nullptr,
                       (const unsigned short*)nullptr);
  }
}

// Round 8
// 760.838 us; speedup vs baseline: 1.0511x; 1.0080x over previous
//
#include <hip/hip_runtime.h>

// v12: v11 + transposed V in LDS. v11 PMC: VALU-busy 650us vs 536us ideal ->
// ~115us unledgered VALU fat. Indicted: PV B-frag assembly (32 scalar
// ds_read_u16 + 16-32 pack VALU per iter; SQ_LDS_BANK_CONFLICT stuck at
// 1.887e7 across 5 versions). Fix: Vst[col][row], col stride 40 shorts
// (80B: 16B-aligned for b128; 20dw -> 8 bank-start classes, uniform 8
// touches/bank). PV B-frag = ONE ds_read_b128 per n at const-base +
// imm-offset n*1280. Staging: 4 scattered b16 writes/chunk (cheap). V
// values / S / P / lsum / threefry mask bit-identical to verified v11.

#define S_LEN 2048
#define D_DIM 64
#define KT    32
#define QT    16
#define NWAVE 4
#define KSTR  72   // K row stride (shorts): b128 frag reads 2-way (free)
#define VTS   40   // V^T col stride (shorts): 80B = 16B-aligned, 8 bank classes
#define PSTR  40   // P row stride (shorts): b128 reads conflict-optimal

typedef short  short8  __attribute__((ext_vector_type(8)));
typedef float  floatx4 __attribute__((ext_vector_type(4)));
typedef unsigned uint2v __attribute__((ext_vector_type(2)));

// Paired threefry2x32 (key (0,42), ctr (0,i)), partitionable form:
// w = x0 ^ x1; drop(i) <=> bit31(w) == 1. Two independent chains interleaved
// (ILP=2). Rotation r -> alignbit shift 32-r. Verified vs C version (v10).
#define TF_R2(sh) \
  "v_add_u32 %1, %1, %0\n\t" \
  "v_add_u32 %3, %3, %2\n\t" \
  "v_alignbit_b32 %0, %0, %0, " #sh "\n\t" \
  "v_alignbit_b32 %2, %2, %2, " #sh "\n\t" \
  "v_xor_b32 %0, %0, %1\n\t" \
  "v_xor_b32 %2, %2, %3\n\t"

__device__ __forceinline__ void tf2(unsigned i0, unsigned i1,
                                    unsigned& w0, unsigned& w1) {
  unsigned a0, a1;
  asm(
    "v_add_u32 %0, 42, %4\n\t"
    "v_add_u32 %2, 42, %5\n\t"
    "v_mov_b32 %1, %0\n\t"
    "v_mov_b32 %3, %2\n\t"
    "v_alignbit_b32 %0, %0, %0, 19\n\t"
    "v_alignbit_b32 %2, %2, %2, 19\n\t"
    "v_xor_b32 %0, %0, %1\n\t"
    "v_xor_b32 %2, %2, %3\n\t"
    TF_R2(17) TF_R2(6) TF_R2(26)
    "v_add_u32 %1, 42, %1\n\t"
    "v_add_u32 %3, 42, %3\n\t"
    "v_add_u32 %0, 0x1bd11bf1, %0\n\t"
    "v_add_u32 %2, 0x1bd11bf1, %2\n\t"
    TF_R2(15) TF_R2(3) TF_R2(16) TF_R2(8)
    "v_add_u32 %1, 0x1bd11bf0, %1\n\t"
    "v_add_u32 %3, 0x1bd11bf0, %3\n\t"
    "v_add_u32 %0, 2, %0\n\t"
    "v_add_u32 %2, 2, %2\n\t"
    TF_R2(19) TF_R2(17) TF_R2(6) TF_R2(26)
    "v_add_u32 %0, 45, %0\n\t"
    "v_add_u32 %2, 45, %2\n\t"
    TF_R2(15) TF_R2(3) TF_R2(16) TF_R2(8)
    "v_add_u32 %1, 42, %1\n\t"
    "v_add_u32 %3, 42, %3\n\t"
    "v_add_u32 %0, 0x1bd11bf4, %0\n\t"
    "v_add_u32 %2, 0x1bd11bf4, %2\n\t"
    TF_R2(19) TF_R2(17) TF_R2(6) TF_R2(26)
    "v_add_u32 %1, 0x1bd11bf0, %1\n\t"
    "v_add_u32 %3, 0x1bd11bf0, %3\n\t"
    "v_add_u32 %0, 5, %0\n\t"
    "v_add_u32 %2, 5, %2\n\t"
    "v_xor_b32 %0, %0, %1\n\t"
    "v_xor_b32 %2, %2, %3"
    : "=&v"(w0), "=&v"(a0), "=&v"(w1), "=&v"(a1)
    : "v"(i0), "v"(i1));
}

__device__ __forceinline__ void split_bf16(float x, unsigned short& h, unsigned short& l) {
  unsigned u = __float_as_uint(x);
  h = (unsigned short)(u >> 16);
  float r = x - __uint_as_float(u & 0xFFFF0000u);
  l = (unsigned short)(__float_as_uint(r) >> 16);
}

#define MFMA(a, b, c) __builtin_amdgcn_mfma_f32_16x16x32_bf16((a), (b), (c), 0, 0, 0)

// ---- prep: split K (f32) into bf16 hi/lo arrays, once. Memory-bound.
__global__ __launch_bounds__(256) void prep_kv(
    const float* __restrict__ Kg, unsigned short* __restrict__ KHg,
    unsigned short* __restrict__ KLg) {
  unsigned t  = blockIdx.x * 256u + threadIdx.x;
  unsigned i4 = t * 4u;                      // 4 elements/thread, 8.4M total
  floatx4 kv = *(const floatx4*)(Kg + i4);
  unsigned short h0, h1, h2, h3, l0, l1, l2, l3;
  split_bf16(kv[0], h0, l0); split_bf16(kv[1], h1, l1);
  split_bf16(kv[2], h2, l2); split_bf16(kv[3], h3, l3);
  uint2v hh, ll;
  hh[0] = (unsigned)h0 | ((unsigned)h1 << 16);
  hh[1] = (unsigned)h2 | ((unsigned)h3 << 16);
  ll[0] = (unsigned)l0 | ((unsigned)l1 << 16);
  ll[1] = (unsigned)l2 | ((unsigned)l3 << 16);
  *(uint2v*)(KHg + i4) = hh;
  *(uint2v*)(KLg + i4) = ll;
}

// ---- fused attention. PREPPED=true: K staged from pre-split bf16 arrays.
template <bool PREPPED>
__global__ __launch_bounds__(256, 6) void attn_v12(
    const float* __restrict__ Qg, const float* __restrict__ Kg,
    const float* __restrict__ Vg, float* __restrict__ Og,
    const unsigned short* __restrict__ KHg,
    const unsigned short* __restrict__ KLg) {

  __shared__ __attribute__((aligned(16))) unsigned short Kh[KT * KSTR];
  __shared__ __attribute__((aligned(16))) unsigned short Kl[KT * KSTR];
  __shared__ __attribute__((aligned(16))) unsigned short Vst[D_DIM * VTS]; // [col][row]
  __shared__ __attribute__((aligned(16))) unsigned short Ph[NWAVE][QT * PSTR];

  const int tid  = threadIdx.x;
  const int wave = tid >> 6;
  const int lane = tid & 63;
  const int m16  = lane & 15;
  const int quad = lane >> 4;

  const int bh    = blockIdx.x >> 5;   // 64 (b,h) heads
  const int qtile = blockIdx.x & 31;   // 32 q-tiles of 64 rows
  const int q0    = qtile * (QT * NWAVE) + wave * QT;
  const size_t head_off = (size_t)bh * S_LEN * D_DIM;

  // Q A-fragments (hi/lo split): A[m=m16][k = kc*32 + quad*8 + j]
  short8 qh[2], ql[2];
#pragma unroll
  for (int kc = 0; kc < 2; ++kc) {
    const float* qp = Qg + head_off + (size_t)(q0 + m16) * D_DIM + kc * 32 + quad * 8;
    floatx4 f0 = *(const floatx4*)qp;
    floatx4 f1 = *(const floatx4*)(qp + 4);
#pragma unroll
    for (int e = 0; e < 4; ++e) {
      unsigned short h, l;
      split_bf16(f0[e], h, l);
      qh[kc][e] = (short)h;  ql[kc][e] = (short)l;
      split_bf16(f1[e], h, l);
      qh[kc][4 + e] = (short)h;  ql[kc][4 + e] = (short)l;
    }
  }

  floatx4 o_acc[4];
#pragma unroll
  for (int n = 0; n < 4; ++n) o_acc[n] = (floatx4){0.f, 0.f, 0.f, 0.f};
  float lsum[4];
#pragma unroll
  for (int r = 0; r < 4; ++r) lsum[r] = 0.f;

  // flat mask index: i = (bh*2048 + q)*2048 + k; q = q0+quad*4+r, k = kb+nb*16+m16
  const unsigned ibase0 =
      ((unsigned)(bh * S_LEN + q0 + quad * 4)) * (unsigned)S_LEN + (unsigned)m16;

  // thread-constant LDS bases (compile-time offsets fold into ds imm fields)
  const unsigned short* kh_rd = &Kh[m16 * KSTR + quad * 8];
  const unsigned short* kl_rd = &Kl[m16 * KSTR + quad * 8];
  const unsigned short* v_rd  = &Vst[m16 * VTS + quad * 8];  // + n*16*VTS
  unsigned short*       p_wr  = &Ph[wave][(quad * 4) * PSTR + m16];
  const unsigned short* p_rd  = &Ph[wave][m16 * PSTR + quad * 8];

  for (int kb = 0; kb < S_LEN; kb += KT) {
    __syncthreads();   // prior iteration's Kh/Kl/Vst reads complete

    // ---- stage K and V into LDS
    if constexpr (PREPPED) {
      // K: pure copy of pre-split bf16 (1 pass, 16B/thread/array)
      const int row = tid >> 3;           // 0..31
      const int c8  = (tid & 7) * 8;      // 0..56
      const size_t koff = head_off + (size_t)(kb + row) * D_DIM + c8;
      short8 kh8 = *(const short8*)(KHg + koff);
      short8 kl8 = *(const short8*)(KLg + koff);
      *(short8*)&Kh[row * KSTR + c8] = kh8;
      *(short8*)&Kl[row * KSTR + c8] = kl8;
      // V: hi-bf16, stored TRANSPOSED: Vst[col][row]
      for (int f = tid; f < KT * (D_DIM / 4); f += 256) {
        int vrow = f >> 4;
        int c4   = (f & 15) << 2;
        floatx4 vv = *(const floatx4*)(Vg + head_off + (size_t)(kb + vrow) * D_DIM + c4);
#pragma unroll
        for (int e = 0; e < 4; ++e)
          Vst[(c4 + e) * VTS + vrow] =
              (unsigned short)(__float_as_uint(vv[e]) >> 16);
      }
    } else {
      // fallback: split K in-kernel; V transposed as above
      for (int f = tid; f < KT * (D_DIM / 4); f += 256) {
        int row = f >> 4;
        int c4  = (f & 15) << 2;
        size_t goff = head_off + (size_t)(kb + row) * D_DIM + c4;
        floatx4 kv = *(const floatx4*)(Kg + goff);
        floatx4 vv = *(const floatx4*)(Vg + goff);
        unsigned short h0, h1, h2, h3, l0, l1, l2, l3;
        split_bf16(kv[0], h0, l0); split_bf16(kv[1], h1, l1);
        split_bf16(kv[2], h2, l2); split_bf16(kv[3], h3, l3);
        int kidx = row * KSTR + c4;
        *(unsigned*)&Kh[kidx]     = (unsigned)h0 | ((unsigned)h1 << 16);
        *(unsigned*)&Kh[kidx + 2] = (unsigned)h2 | ((unsigned)h3 << 16);
        *(unsigned*)&Kl[kidx]     = (unsigned)l0 | ((unsigned)l1 << 16);
        *(unsigned*)&Kl[kidx + 2] = (unsigned)l2 | ((unsigned)l3 << 16);
#pragma unroll
        for (int e = 0; e < 4; ++e)
          Vst[(c4 + e) * VTS + row] =
              (unsigned short)(__float_as_uint(vv[e]) >> 16);
      }
    }
    __syncthreads();

    // ---- S = Q K^T (split-bf16 3-term: hh + hl + lh)
    floatx4 sc[2];
#pragma unroll
    for (int nb = 0; nb < 2; ++nb) {
      floatx4 acc = (floatx4){0.f, 0.f, 0.f, 0.f};
#pragma unroll
      for (int kc = 0; kc < 2; ++kc) {
        short8 kbh = *(const short8*)&kh_rd[nb * 16 * KSTR + kc * 32];
        short8 kbl = *(const short8*)&kl_rd[nb * 16 * KSTR + kc * 32];
        acc = MFMA(qh[kc], kbh, acc);
        acc = MFMA(qh[kc], kbl, acc);
        acc = MFMA(ql[kc], kbh, acc);
      }
      sc[nb] = acc;
    }

    // ---- p = exp(s), per-lane l partial, asm-threefry mask, P -> LDS
#pragma unroll
    for (int r = 0; r < 4; ++r) {
      unsigned i0 = ibase0 + (unsigned)kb + (unsigned)(r * S_LEN);
      unsigned w0, w1;
      tf2(i0, i0 + 16u, w0, w1);   // nb=0, nb=1
#pragma unroll
      for (int nb = 0; nb < 2; ++nb) {
        float pe = __expf(sc[nb][r]);
        lsum[r] += pe;
        unsigned hbits = __float_as_uint(pe) >> 16;
        unsigned w = nb ? w1 : w0;
        hbits = ((int)w < 0) ? 0u : hbits;   // bit31(w)=1 -> drop
        p_wr[r * PSTR + nb * 16] = (unsigned short)hbits;
      }
    }
    // Ph is wave-private; same-wave LDS RAW handled by lgkmcnt.

    // ---- O += P V: B-frag is ONE b128 per n from transposed V
    short8 pa = *(const short8*)p_rd;
#pragma unroll
    for (int n = 0; n < 4; ++n) {
      short8 vb = *(const short8*)&v_rd[n * 16 * VTS];
      o_acc[n] = MFMA(pa, vb, o_acc[n]);
    }
  }

  // ---- final l reduction over the 16 m16 lanes
#pragma unroll
  for (int off = 8; off >= 1; off >>= 1)
#pragma unroll
    for (int r = 0; r < 4; ++r)
      lsum[r] += __shfl_xor(lsum[r], off, 64);

  // ---- epilogue: out = O * (2 / l)   (2 = 1/(1-p) dropout scale)
#pragma unroll
  for (int r = 0; r < 4; ++r) {
    float scale = 2.0f / lsum[r];
#pragma unroll
    for (int n = 0; n < 4; ++n) {
      Og[head_off + (size_t)(q0 + quad * 4 + r) * D_DIM + n * 16 + m16] =
          o_acc[n][r] * scale;
    }
  }
}

extern "C" void kernel_launch(void* const* d_in, const int* in_sizes, int n_in,
                              void* d_out, int out_size, void* d_ws, size_t ws_size,
                              hipStream_t stream) {
  (void)in_sizes; (void)n_in; (void)out_size;
  const float* Q = (const float*)d_in[0];
  const float* K = (const float*)d_in[1];
  const float* V = (const float*)d_in[2];
  float* O = (float*)d_out;

  const size_t KELTS = (size_t)64 * S_LEN * D_DIM;          // 8,388,608
  const size_t NEED  = 2 * KELTS * sizeof(unsigned short);  // 33,554,432 B
  if (d_ws != nullptr && ws_size >= NEED) {
    unsigned short* KH = (unsigned short*)d_ws;
    unsigned short* KL = KH + KELTS;
    hipLaunchKernelGGL(prep_kv, dim3((unsigned)(KELTS / 4 / 256)), dim3(256),
                       0, stream, K, KH, KL);
    hipLaunchKernelGGL((attn_v12<true>), dim3(2048), dim3(256), 0, stream,
                       Q, K, V, O, KH, KL);
  } else {
    hipLaunchKernelGGL((attn_v12<false>), dim3(2048), dim3(256), 0, stream,
                       Q, K, V, O, (const unsigned short*)nullptr,
                       (const unsigned short*)nullptr);
  }
}

// Round 9
// 744.634 us; speedup vs baseline: 1.0740x; 1.0218x over previous
//
#include <hip/hip_runtime.h>

// v13: barrier-free attention. v12 ledger: 745 = 478 (threefry floor @1.2GHz
// sustained) + ~150 other-VALU + ~115 STALL (2 __syncthreads x 64 iters
// draining vmcnt/lgkmcnt). v12's conflict counter (1.9e7 -> 8.6e7) proved
// staging-write conflicts eat the PV-read gain. Fix both at once: no block-
// shared LDS at all. K (pre-split hi/lo) and V (pre-transposed, tiled) live
// in ws; each wave loads its fragments DIRECTLY from global — every load is
// a contiguous 1-2KB wave segment, 4x redundant across waves but L2-hot
// (~3MB/XCD working set). Only LDS: wave-private P exchange (no barrier;
// same-wave RAW via lgkmcnt, proven v6-v12). Loop has zero barriers.
// ws = KH(16M) + KL(16M) + VT(16M) = 48MiB; proven >=33.5M, >=48 unknown ->
// fallback = verified v10 monolith (770us), which brackets ws_size.

#define S_LEN 2048
#define D_DIM 64
#define KT    32
#define QT    16
#define NWAVE 4
#define KSTR  72   // (fallback) K row stride
#define VROW  66   // (fallback) V row stride
#define PSTR  40   // P row stride (shorts)

typedef short  short8  __attribute__((ext_vector_type(8)));
typedef float  floatx4 __attribute__((ext_vector_type(4)));
typedef unsigned uint2v __attribute__((ext_vector_type(2)));

// Paired threefry2x32 (key (0,42), ctr (0,i)): w = x0^x1; drop <=> bit31(w).
// Two independent chains interleaved (ILP=2). Verified (v10/v11/v12 passed).
#define TF_R2(sh) \
  "v_add_u32 %1, %1, %0\n\t" \
  "v_add_u32 %3, %3, %2\n\t" \
  "v_alignbit_b32 %0, %0, %0, " #sh "\n\t" \
  "v_alignbit_b32 %2, %2, %2, " #sh "\n\t" \
  "v_xor_b32 %0, %0, %1\n\t" \
  "v_xor_b32 %2, %2, %3\n\t"

__device__ __forceinline__ void tf2(unsigned i0, unsigned i1,
                                    unsigned& w0, unsigned& w1) {
  unsigned a0, a1;
  asm(
    "v_add_u32 %0, 42, %4\n\t"
    "v_add_u32 %2, 42, %5\n\t"
    "v_mov_b32 %1, %0\n\t"
    "v_mov_b32 %3, %2\n\t"
    "v_alignbit_b32 %0, %0, %0, 19\n\t"
    "v_alignbit_b32 %2, %2, %2, 19\n\t"
    "v_xor_b32 %0, %0, %1\n\t"
    "v_xor_b32 %2, %2, %3\n\t"
    TF_R2(17) TF_R2(6) TF_R2(26)
    "v_add_u32 %1, 42, %1\n\t"
    "v_add_u32 %3, 42, %3\n\t"
    "v_add_u32 %0, 0x1bd11bf1, %0\n\t"
    "v_add_u32 %2, 0x1bd11bf1, %2\n\t"
    TF_R2(15) TF_R2(3) TF_R2(16) TF_R2(8)
    "v_add_u32 %1, 0x1bd11bf0, %1\n\t"
    "v_add_u32 %3, 0x1bd11bf0, %3\n\t"
    "v_add_u32 %0, 2, %0\n\t"
    "v_add_u32 %2, 2, %2\n\t"
    TF_R2(19) TF_R2(17) TF_R2(6) TF_R2(26)
    "v_add_u32 %0, 45, %0\n\t"
    "v_add_u32 %2, 45, %2\n\t"
    TF_R2(15) TF_R2(3) TF_R2(16) TF_R2(8)
    "v_add_u32 %1, 42, %1\n\t"
    "v_add_u32 %3, 42, %3\n\t"
    "v_add_u32 %0, 0x1bd11bf4, %0\n\t"
    "v_add_u32 %2, 0x1bd11bf4, %2\n\t"
    TF_R2(19) TF_R2(17) TF_R2(6) TF_R2(26)
    "v_add_u32 %1, 0x1bd11bf0, %1\n\t"
    "v_add_u32 %3, 0x1bd11bf0, %3\n\t"
    "v_add_u32 %0, 5, %0\n\t"
    "v_add_u32 %2, 5, %2\n\t"
    "v_xor_b32 %0, %0, %1\n\t"
    "v_xor_b32 %2, %2, %3"
    : "=&v"(w0), "=&v"(a0), "=&v"(w1), "=&v"(a1)
    : "v"(i0), "v"(i1));
}

__device__ __forceinline__ void split_bf16(float x, unsigned short& h, unsigned short& l) {
  unsigned u = __float_as_uint(x);
  h = (unsigned short)(u >> 16);
  float r = x - __uint_as_float(u & 0xFFFF0000u);
  l = (unsigned short)(__float_as_uint(r) >> 16);
}

#define MFMA(a, b, c) __builtin_amdgcn_mfma_f32_16x16x32_bf16((a), (b), (c), 0, 0, 0)

// ---- prep 1: split K (f32) into bf16 hi/lo arrays. Memory-bound.
__global__ __launch_bounds__(256) void prep_k(
    const float* __restrict__ Kg, unsigned short* __restrict__ KHg,
    unsigned short* __restrict__ KLg) {
  unsigned t  = blockIdx.x * 256u + threadIdx.x;
  unsigned i4 = t * 4u;
  floatx4 kv = *(const floatx4*)(Kg + i4);
  unsigned short h0, h1, h2, h3, l0, l1, l2, l3;
  split_bf16(kv[0], h0, l0); split_bf16(kv[1], h1, l1);
  split_bf16(kv[2], h2, l2); split_bf16(kv[3], h3, l3);
  uint2v hh, ll;
  hh[0] = (unsigned)h0 | ((unsigned)h1 << 16);
  hh[1] = (unsigned)h2 | ((unsigned)h3 << 16);
  ll[0] = (unsigned)l0 | ((unsigned)l1 << 16);
  ll[1] = (unsigned)l2 | ((unsigned)l3 << 16);
  *(uint2v*)(KHg + i4) = hh;
  *(uint2v*)(KLg + i4) = ll;
}

// ---- prep 2: per-head per-32-row-tile transpose of V (hi bf16).
// VT[bh][tile][col][row], row in [0,32): flat = ((bh*64+tile)*64+col)*32+row.
__global__ __launch_bounds__(256) void prep_vt(
    const float* __restrict__ Vg, unsigned short* __restrict__ VTg) {
  __shared__ unsigned short T[D_DIM][40];   // [col][row], padded
  const int bh   = blockIdx.x >> 6;
  const int tile = blockIdx.x & 63;
  const int tid  = threadIdx.x;
  const int row  = tid >> 3;              // 0..31
  const int c8   = (tid & 7) * 8;         // 0..56
  const float* vp = Vg + (size_t)bh * S_LEN * D_DIM + (size_t)(tile * 32 + row) * D_DIM + c8;
  floatx4 v0 = *(const floatx4*)vp;
  floatx4 v1 = *(const floatx4*)(vp + 4);
#pragma unroll
  for (int e = 0; e < 4; ++e) {
    T[c8 + e][row]     = (unsigned short)(__float_as_uint(v0[e]) >> 16);
    T[c8 + 4 + e][row] = (unsigned short)(__float_as_uint(v1[e]) >> 16);
  }
  __syncthreads();
  // coalesced write-out: thread t -> shorts [t*8, t*8+8) of the 2048-short tile
  const int col = tid >> 2;
  const int r0  = (tid & 3) * 8;
  short8 out = *(const short8*)&T[col][r0];
  *(short8*)(VTg + ((size_t)blockIdx.x * D_DIM) * 32 + (size_t)tid * 8) = out;
}

// ---- barrier-free fused attention (needs KH/KL/VT in ws).
__global__ __launch_bounds__(256, 4) void attn_v13(
    const float* __restrict__ Qg, float* __restrict__ Og,
    const unsigned short* __restrict__ KHg,
    const unsigned short* __restrict__ KLg,
    const unsigned short* __restrict__ VTg) {

  __shared__ __attribute__((aligned(16))) unsigned short Ph[NWAVE][QT * PSTR];

  const int tid  = threadIdx.x;
  const int wave = tid >> 6;
  const int lane = tid & 63;
  const int m16  = lane & 15;
  const int quad = lane >> 4;

  const int bh    = blockIdx.x >> 5;
  const int qtile = blockIdx.x & 31;
  const int q0    = qtile * (QT * NWAVE) + wave * QT;
  const size_t head_off = (size_t)bh * S_LEN * D_DIM;

  // Q A-fragments (hi/lo split)
  short8 qh[2], ql[2];
#pragma unroll
  for (int kc = 0; kc < 2; ++kc) {
    const float* qp = Qg + head_off + (size_t)(q0 + m16) * D_DIM + kc * 32 + quad * 8;
    floatx4 f0 = *(const floatx4*)qp;
    floatx4 f1 = *(const floatx4*)(qp + 4);
#pragma unroll
    for (int e = 0; e < 4; ++e) {
      unsigned short h, l;
      split_bf16(f0[e], h, l);
      qh[kc][e] = (short)h;  ql[kc][e] = (short)l;
      split_bf16(f1[e], h, l);
      qh[kc][4 + e] = (short)h;  ql[kc][4 + e] = (short)l;
    }
  }

  floatx4 o_acc[4];
#pragma unroll
  for (int n = 0; n < 4; ++n) o_acc[n] = (floatx4){0.f, 0.f, 0.f, 0.f};
  float lsum[4];
#pragma unroll
  for (int r = 0; r < 4; ++r) lsum[r] = 0.f;

  const unsigned ibase0 =
      ((unsigned)(bh * S_LEN + q0 + quad * 4)) * (unsigned)S_LEN + (unsigned)m16;

  // thread-constant global fragment bases
  const unsigned short* khp = KHg + head_off + (size_t)(m16 * D_DIM + quad * 8);
  const unsigned short* klp = KLg + head_off + (size_t)(m16 * D_DIM + quad * 8);
  const unsigned short* vtp = VTg + head_off + (size_t)(m16 * 32 + quad * 8);

  unsigned short*       p_wr = &Ph[wave][(quad * 4) * PSTR + m16];
  const unsigned short* p_rd = &Ph[wave][m16 * PSTR + quad * 8];

  for (int kb = 0; kb < S_LEN; kb += KT) {
    // ---- issue all fragment loads (contiguous 1-2KB per wave instr, L2-hot)
    const unsigned short* kh_i = khp + (size_t)kb * D_DIM;
    const unsigned short* kl_i = klp + (size_t)kb * D_DIM;
    const unsigned short* vt_i = vtp + (size_t)(kb >> 5) * (D_DIM * 32);
    short8 kfh[2][2], kfl[2][2], vf[4];
#pragma unroll
    for (int nb = 0; nb < 2; ++nb)
#pragma unroll
      for (int kc = 0; kc < 2; ++kc) {
        kfh[nb][kc] = *(const short8*)(kh_i + nb * 16 * D_DIM + kc * 32);
        kfl[nb][kc] = *(const short8*)(kl_i + nb * 16 * D_DIM + kc * 32);
      }
#pragma unroll
    for (int n = 0; n < 4; ++n)
      vf[n] = *(const short8*)(vt_i + n * 16 * 32);

    // ---- threefry (VALU block; loads land underneath)
    unsigned w[8];
#pragma unroll
    for (int r = 0; r < 4; ++r) {
      unsigned i0 = ibase0 + (unsigned)kb + (unsigned)(r * S_LEN);
      tf2(i0, i0 + 16u, w[r * 2], w[r * 2 + 1]);
    }

    // ---- S = Q K^T (hh + hl + lh)
    floatx4 sc[2];
#pragma unroll
    for (int nb = 0; nb < 2; ++nb) {
      floatx4 acc = (floatx4){0.f, 0.f, 0.f, 0.f};
#pragma unroll
      for (int kc = 0; kc < 2; ++kc) {
        acc = MFMA(qh[kc], kfh[nb][kc], acc);
        acc = MFMA(qh[kc], kfl[nb][kc], acc);
        acc = MFMA(ql[kc], kfh[nb][kc], acc);
      }
      sc[nb] = acc;
    }

    // ---- p = exp(s), mask, P -> LDS (wave-private; no barrier)
#pragma unroll
    for (int r = 0; r < 4; ++r)
#pragma unroll
      for (int nb = 0; nb < 2; ++nb) {
        float pe = __expf(sc[nb][r]);
        lsum[r] += pe;
        unsigned hbits = __float_as_uint(pe) >> 16;
        hbits = ((int)w[r * 2 + nb] < 0) ? 0u : hbits;
        p_wr[r * PSTR + nb * 16] = (unsigned short)hbits;
      }

    // ---- O += P V (B-frag = preloaded vf)
    short8 pa = *(const short8*)p_rd;
#pragma unroll
    for (int n = 0; n < 4; ++n)
      o_acc[n] = MFMA(pa, vf[n], o_acc[n]);
  }

#pragma unroll
  for (int off = 8; off >= 1; off >>= 1)
#pragma unroll
    for (int r = 0; r < 4; ++r)
      lsum[r] += __shfl_xor(lsum[r], off, 64);

#pragma unroll
  for (int r = 0; r < 4; ++r) {
    float scale = 2.0f / lsum[r];
#pragma unroll
    for (int n = 0; n < 4; ++n) {
      Og[head_off + (size_t)(q0 + quad * 4 + r) * D_DIM + n * 16 + m16] =
          o_acc[n][r] * scale;
    }
  }
}

// ---- fallback monolith (verified v10, 770us): in-kernel split + LDS staging.
__global__ __launch_bounds__(256, 6) void attn_mono(
    const float* __restrict__ Qg, const float* __restrict__ Kg,
    const float* __restrict__ Vg, float* __restrict__ Og) {

  __shared__ __attribute__((aligned(16))) unsigned short Kh[KT * KSTR];
  __shared__ __attribute__((aligned(16))) unsigned short Kl[KT * KSTR];
  __shared__ __attribute__((aligned(16))) unsigned short Vs[KT * VROW];
  __shared__ __attribute__((aligned(16))) unsigned short Ph[NWAVE][QT * PSTR];

  const int tid  = threadIdx.x;
  const int wave = tid >> 6;
  const int lane = tid & 63;
  const int m16  = lane & 15;
  const int quad = lane >> 4;

  const int bh    = blockIdx.x >> 5;
  const int qtile = blockIdx.x & 31;
  const int q0    = qtile * (QT * NWAVE) + wave * QT;
  const size_t head_off = (size_t)bh * S_LEN * D_DIM;

  short8 qh[2], ql[2];
#pragma unroll
  for (int kc = 0; kc < 2; ++kc) {
    const float* qp = Qg + head_off + (size_t)(q0 + m16) * D_DIM + kc * 32 + quad * 8;
    floatx4 f0 = *(const floatx4*)qp;
    floatx4 f1 = *(const floatx4*)(qp + 4);
#pragma unroll
    for (int e = 0; e < 4; ++e) {
      unsigned short h, l;
      split_bf16(f0[e], h, l);
      qh[kc][e] = (short)h;  ql[kc][e] = (short)l;
      split_bf16(f1[e], h, l);
      qh[kc][4 + e] = (short)h;  ql[kc][4 + e] = (short)l;
    }
  }

  floatx4 o_acc[4];
#pragma unroll
  for (int n = 0; n < 4; ++n) o_acc[n] = (floatx4){0.f, 0.f, 0.f, 0.f};
  float lsum[4];
#pragma unroll
  for (int r = 0; r < 4; ++r) lsum[r] = 0.f;

  const unsigned ibase0 =
      ((unsigned)(bh * S_LEN + q0 + quad * 4)) * (unsigned)S_LEN + (unsigned)m16;

  for (int kb = 0; kb < S_LEN; kb += KT) {
    __syncthreads();
    for (int f = tid; f < KT * (D_DIM / 4); f += 256) {
      int row = f >> 4;
      int c4  = (f & 15) << 2;
      size_t goff = head_off + (size_t)(kb + row) * D_DIM + c4;
      floatx4 kv = *(const floatx4*)(Kg + goff);
      floatx4 vv = *(const floatx4*)(Vg + goff);
      unsigned short h0, h1, h2, h3, l0, l1, l2, l3;
      split_bf16(kv[0], h0, l0); split_bf16(kv[1], h1, l1);
      split_bf16(kv[2], h2, l2); split_bf16(kv[3], h3, l3);
      int kidx = row * KSTR + c4;
      *(unsigned*)&Kh[kidx]     = (unsigned)h0 | ((unsigned)h1 << 16);
      *(unsigned*)&Kh[kidx + 2] = (unsigned)h2 | ((unsigned)h3 << 16);
      *(unsigned*)&Kl[kidx]     = (unsigned)l0 | ((unsigned)l1 << 16);
      *(unsigned*)&Kl[kidx + 2] = (unsigned)l2 | ((unsigned)l3 << 16);
      unsigned v01 = (__float_as_uint(vv[0]) >> 16) |
                     (__float_as_uint(vv[1]) & 0xFFFF0000u);
      unsigned v23 = (__float_as_uint(vv[2]) >> 16) |
                     (__float_as_uint(vv[3]) & 0xFFFF0000u);
      int vidx = row * VROW + c4;
      *(unsigned*)&Vs[vidx]     = v01;
      *(unsigned*)&Vs[vidx + 2] = v23;
    }
    __syncthreads();

    floatx4 sc[2];
#pragma unroll
    for (int nb = 0; nb < 2; ++nb) {
      floatx4 acc = (floatx4){0.f, 0.f, 0.f, 0.f};
#pragma unroll
      for (int kc = 0; kc < 2; ++kc) {
        int bidx = (nb * 16 + m16) * KSTR + kc * 32 + quad * 8;
        short8 kbh = *(const short8*)&Kh[bidx];
        short8 kbl = *(const short8*)&Kl[bidx];
        acc = MFMA(qh[kc], kbh, acc);
        acc = MFMA(qh[kc], kbl, acc);
        acc = MFMA(ql[kc], kbh, acc);
      }
      sc[nb] = acc;
    }

#pragma unroll
    for (int r = 0; r < 4; ++r) {
      unsigned i0 = ibase0 + (unsigned)kb + (unsigned)(r * S_LEN);
      unsigned w0, w1;
      tf2(i0, i0 + 16u, w0, w1);
#pragma unroll
      for (int nb = 0; nb < 2; ++nb) {
        float pe = __expf(sc[nb][r]);
        lsum[r] += pe;
        unsigned hbits = __float_as_uint(pe) >> 16;
        unsigned w = nb ? w1 : w0;
        hbits = ((int)w < 0) ? 0u : hbits;
        Ph[wave][(quad * 4 + r) * PSTR + nb * 16 + m16] = (unsigned short)hbits;
      }
    }

    short8 pa = *(const short8*)&Ph[wave][m16 * PSTR + quad * 8];
#pragma unroll
    for (int n = 0; n < 4; ++n) {
      short8 vb;
#pragma unroll
      for (int j = 0; j < 8; ++j)
        vb[j] = (short)Vs[(quad * 8 + j) * VROW + n * 16 + m16];
      o_acc[n] = MFMA(pa, vb, o_acc[n]);
    }
  }

#pragma unroll
  for (int off = 8; off >= 1; off >>= 1)
#pragma unroll
    for (int r = 0; r < 4; ++r)
      lsum[r] += __shfl_xor(lsum[r], off, 64);

#pragma unroll
  for (int r = 0; r < 4; ++r) {
    float scale = 2.0f / lsum[r];
#pragma unroll
    for (int n = 0; n < 4; ++n) {
      Og[head_off + (size_t)(q0 + quad * 4 + r) * D_DIM + n * 16 + m16] =
          o_acc[n][r] * scale;
    }
  }
}

extern "C" void kernel_launch(void* const* d_in, const int* in_sizes, int n_in,
                              void* d_out, int out_size, void* d_ws, size_t ws_size,
                              hipStream_t stream) {
  (void)in_sizes; (void)n_in; (void)out_size;
  const float* Q = (const float*)d_in[0];
  const float* K = (const float*)d_in[1];
  const float* V = (const float*)d_in[2];
  float* O = (float*)d_out;

  const size_t KELTS = (size_t)64 * S_LEN * D_DIM;              // 8,388,608
  const size_t NEED  = 3 * KELTS * sizeof(unsigned short);      // 48 MiB
  if (d_ws != nullptr && ws_size >= NEED) {
    unsigned short* KH = (unsigned short*)d_ws;
    unsigned short* KL = KH + KELTS;
    unsigned short* VT = KL + KELTS;
    hipLaunchKernelGGL(prep_k, dim3((unsigned)(KELTS / 4 / 256)), dim3(256),
                       0, stream, K, KH, KL);
    hipLaunchKernelGGL(prep_vt, dim3(64 * 64), dim3(256), 0, stream, V, VT);
    hipLaunchKernelGGL(attn_v13, dim3(2048), dim3(256), 0, stream, Q, O, KH, KL, VT);
  } else {
    hipLaunchKernelGGL(attn_mono, dim3(2048), dim3(256), 0, stream, Q, K, V, O);
  }
}

// Round 10
// 743.789 us; speedup vs baseline: 1.0752x; 1.0011x over previous
//
#include <hip/hip_runtime.h>

// v14: v13 (barrier-free, 712us attn) + software-pipelined P exchange +
// merged prep. v13 ledger: 619us VALU-busy (87%), 93us stall. Only in-loop
// latency chain left: P LDS write->read same-iter (~120cy, nothing between).
// Fix: Ph[2] double-buffer — write tile t, read tile t-1; PV MFMAs for t-1
// issue BEFORE tile t's 568-instr threefry block (MFMA pipe co-schedules
// with VALU, m114). o_acc accumulation order preserved (tiles in order) —
// output bit-identical. Preps merged into one block-split kernel (-1 launch).
// ws >= 48MiB proven by v13's PREPPED path having run.

#define S_LEN 2048
#define D_DIM 64
#define KT    32
#define QT    16
#define NWAVE 4
#define KSTR  72   // (fallback) K row stride
#define VROW  66   // (fallback) V row stride
#define PSTR  40   // P row stride (shorts)

typedef short  short8  __attribute__((ext_vector_type(8)));
typedef float  floatx4 __attribute__((ext_vector_type(4)));
typedef unsigned uint2v __attribute__((ext_vector_type(2)));

// Paired threefry2x32 (key (0,42), ctr (0,i)): w = x0^x1; drop <=> bit31(w).
// Two independent chains interleaved (ILP=2). Verified v10-v13.
#define TF_R2(sh) \
  "v_add_u32 %1, %1, %0\n\t" \
  "v_add_u32 %3, %3, %2\n\t" \
  "v_alignbit_b32 %0, %0, %0, " #sh "\n\t" \
  "v_alignbit_b32 %2, %2, %2, " #sh "\n\t" \
  "v_xor_b32 %0, %0, %1\n\t" \
  "v_xor_b32 %2, %2, %3\n\t"

__device__ __forceinline__ void tf2(unsigned i0, unsigned i1,
                                    unsigned& w0, unsigned& w1) {
  unsigned a0, a1;
  asm(
    "v_add_u32 %0, 42, %4\n\t"
    "v_add_u32 %2, 42, %5\n\t"
    "v_mov_b32 %1, %0\n\t"
    "v_mov_b32 %3, %2\n\t"
    "v_alignbit_b32 %0, %0, %0, 19\n\t"
    "v_alignbit_b32 %2, %2, %2, 19\n\t"
    "v_xor_b32 %0, %0, %1\n\t"
    "v_xor_b32 %2, %2, %3\n\t"
    TF_R2(17) TF_R2(6) TF_R2(26)
    "v_add_u32 %1, 42, %1\n\t"
    "v_add_u32 %3, 42, %3\n\t"
    "v_add_u32 %0, 0x1bd11bf1, %0\n\t"
    "v_add_u32 %2, 0x1bd11bf1, %2\n\t"
    TF_R2(15) TF_R2(3) TF_R2(16) TF_R2(8)
    "v_add_u32 %1, 0x1bd11bf0, %1\n\t"
    "v_add_u32 %3, 0x1bd11bf0, %3\n\t"
    "v_add_u32 %0, 2, %0\n\t"
    "v_add_u32 %2, 2, %2\n\t"
    TF_R2(19) TF_R2(17) TF_R2(6) TF_R2(26)
    "v_add_u32 %0, 45, %0\n\t"
    "v_add_u32 %2, 45, %2\n\t"
    TF_R2(15) TF_R2(3) TF_R2(16) TF_R2(8)
    "v_add_u32 %1, 42, %1\n\t"
    "v_add_u32 %3, 42, %3\n\t"
    "v_add_u32 %0, 0x1bd11bf4, %0\n\t"
    "v_add_u32 %2, 0x1bd11bf4, %2\n\t"
    TF_R2(19) TF_R2(17) TF_R2(6) TF_R2(26)
    "v_add_u32 %1, 0x1bd11bf0, %1\n\t"
    "v_add_u32 %3, 0x1bd11bf0, %3\n\t"
    "v_add_u32 %0, 5, %0\n\t"
    "v_add_u32 %2, 5, %2\n\t"
    "v_xor_b32 %0, %0, %1\n\t"
    "v_xor_b32 %2, %2, %3"
    : "=&v"(w0), "=&v"(a0), "=&v"(w1), "=&v"(a1)
    : "v"(i0), "v"(i1));
}

__device__ __forceinline__ void split_bf16(float x, unsigned short& h, unsigned short& l) {
  unsigned u = __float_as_uint(x);
  h = (unsigned short)(u >> 16);
  float r = x - __uint_as_float(u & 0xFFFF0000u);
  l = (unsigned short)(__float_as_uint(r) >> 16);
}

#define MFMA(a, b, c) __builtin_amdgcn_mfma_f32_16x16x32_bf16((a), (b), (c), 0, 0, 0)

// ---- merged prep: blocks [0,8192) split K into bf16 hi/lo; blocks
// [8192,12288) transpose V (hi bf16) per 32-row tile. Memory-bound.
__global__ __launch_bounds__(256) void prep_all(
    const float* __restrict__ Kg, const float* __restrict__ Vg,
    unsigned short* __restrict__ KHg, unsigned short* __restrict__ KLg,
    unsigned short* __restrict__ VTg) {
  __shared__ unsigned short T[D_DIM][40];   // [col][row], padded (V part)
  if (blockIdx.x < 8192) {
    unsigned t  = blockIdx.x * 256u + threadIdx.x;
    unsigned i4 = t * 4u;
    floatx4 kv = *(const floatx4*)(Kg + i4);
    unsigned short h0, h1, h2, h3, l0, l1, l2, l3;
    split_bf16(kv[0], h0, l0); split_bf16(kv[1], h1, l1);
    split_bf16(kv[2], h2, l2); split_bf16(kv[3], h3, l3);
    uint2v hh, ll;
    hh[0] = (unsigned)h0 | ((unsigned)h1 << 16);
    hh[1] = (unsigned)h2 | ((unsigned)h3 << 16);
    ll[0] = (unsigned)l0 | ((unsigned)l1 << 16);
    ll[1] = (unsigned)l2 | ((unsigned)l3 << 16);
    *(uint2v*)(KHg + i4) = hh;
    *(uint2v*)(KLg + i4) = ll;
  } else {
    const int bid  = blockIdx.x - 8192;
    const int bh   = bid >> 6;
    const int tile = bid & 63;
    const int tid  = threadIdx.x;
    const int row  = tid >> 3;              // 0..31
    const int c8   = (tid & 7) * 8;         // 0..56
    const float* vp = Vg + (size_t)bh * S_LEN * D_DIM +
                      (size_t)(tile * 32 + row) * D_DIM + c8;
    floatx4 v0 = *(const floatx4*)vp;
    floatx4 v1 = *(const floatx4*)(vp + 4);
#pragma unroll
    for (int e = 0; e < 4; ++e) {
      T[c8 + e][row]     = (unsigned short)(__float_as_uint(v0[e]) >> 16);
      T[c8 + 4 + e][row] = (unsigned short)(__float_as_uint(v1[e]) >> 16);
    }
    __syncthreads();
    const int col = tid >> 2;
    const int r0  = (tid & 3) * 8;
    short8 out = *(const short8*)&T[col][r0];
    *(short8*)(VTg + ((size_t)bid * D_DIM) * 32 + (size_t)tid * 8) = out;
  }
}

// ---- barrier-free fused attention, pipelined P exchange (needs KH/KL/VT).
__global__ __launch_bounds__(256, 4) void attn_v14(
    const float* __restrict__ Qg, float* __restrict__ Og,
    const unsigned short* __restrict__ KHg,
    const unsigned short* __restrict__ KLg,
    const unsigned short* __restrict__ VTg) {

  __shared__ __attribute__((aligned(16))) unsigned short Ph[2][NWAVE][QT * PSTR];

  const int tid  = threadIdx.x;
  const int wave = tid >> 6;
  const int lane = tid & 63;
  const int m16  = lane & 15;
  const int quad = lane >> 4;

  const int bh    = blockIdx.x >> 5;
  const int qtile = blockIdx.x & 31;
  const int q0    = qtile * (QT * NWAVE) + wave * QT;
  const size_t head_off = (size_t)bh * S_LEN * D_DIM;

  // Q A-fragments (hi/lo split)
  short8 qh[2], ql[2];
#pragma unroll
  for (int kc = 0; kc < 2; ++kc) {
    const float* qp = Qg + head_off + (size_t)(q0 + m16) * D_DIM + kc * 32 + quad * 8;
    floatx4 f0 = *(const floatx4*)qp;
    floatx4 f1 = *(const floatx4*)(qp + 4);
#pragma unroll
    for (int e = 0; e < 4; ++e) {
      unsigned short h, l;
      split_bf16(f0[e], h, l);
      qh[kc][e] = (short)h;  ql[kc][e] = (short)l;
      split_bf16(f1[e], h, l);
      qh[kc][4 + e] = (short)h;  ql[kc][4 + e] = (short)l;
    }
  }

  floatx4 o_acc[4];
#pragma unroll
  for (int n = 0; n < 4; ++n) o_acc[n] = (floatx4){0.f, 0.f, 0.f, 0.f};
  float lsum[4];
#pragma unroll
  for (int r = 0; r < 4; ++r) lsum[r] = 0.f;

  const unsigned ibase0 =
      ((unsigned)(bh * S_LEN + q0 + quad * 4)) * (unsigned)S_LEN + (unsigned)m16;

  // thread-constant global fragment bases
  const unsigned short* khp = KHg + head_off + (size_t)(m16 * D_DIM + quad * 8);
  const unsigned short* klp = KLg + head_off + (size_t)(m16 * D_DIM + quad * 8);
  const unsigned short* vtp = VTg + head_off + (size_t)(m16 * 32 + quad * 8);

  unsigned short*       p_wr0 = &Ph[0][wave][(quad * 4) * PSTR + m16];
  const unsigned short* p_rd0 = &Ph[0][wave][m16 * PSTR + quad * 8];
  const int PBUF = NWAVE * QT * PSTR;   // shorts per buffer

  short8 vf_prev[4];
  int cur = 0;

  // ================= prologue: tile 0 (no PV yet) =================
  {
    short8 kfh[2][2], kfl[2][2];
#pragma unroll
    for (int nb = 0; nb < 2; ++nb)
#pragma unroll
      for (int kc = 0; kc < 2; ++kc) {
        kfh[nb][kc] = *(const short8*)(khp + nb * 16 * D_DIM + kc * 32);
        kfl[nb][kc] = *(const short8*)(klp + nb * 16 * D_DIM + kc * 32);
      }
#pragma unroll
    for (int n = 0; n < 4; ++n)
      vf_prev[n] = *(const short8*)(vtp + n * 16 * 32);

    unsigned w[8];
#pragma unroll
    for (int r = 0; r < 4; ++r) {
      unsigned i0 = ibase0 + (unsigned)(r * S_LEN);
      tf2(i0, i0 + 16u, w[r * 2], w[r * 2 + 1]);
    }

    floatx4 sc[2];
#pragma unroll
    for (int nb = 0; nb < 2; ++nb) {
      floatx4 acc = (floatx4){0.f, 0.f, 0.f, 0.f};
#pragma unroll
      for (int kc = 0; kc < 2; ++kc) {
        acc = MFMA(qh[kc], kfh[nb][kc], acc);
        acc = MFMA(qh[kc], kfl[nb][kc], acc);
        acc = MFMA(ql[kc], kfh[nb][kc], acc);
      }
      sc[nb] = acc;
    }

#pragma unroll
    for (int r = 0; r < 4; ++r)
#pragma unroll
      for (int nb = 0; nb < 2; ++nb) {
        float pe = __expf(sc[nb][r]);
        lsum[r] += pe;
        unsigned hbits = __float_as_uint(pe) >> 16;
        hbits = ((int)w[r * 2 + nb] < 0) ? 0u : hbits;
        p_wr0[r * PSTR + nb * 16] = (unsigned short)hbits;
      }
  }

  // ================= main loop: tiles 1..63 =================
  for (int kb = KT; kb < S_LEN; kb += KT) {
    const unsigned short* kh_i = khp + (size_t)kb * D_DIM;
    const unsigned short* kl_i = klp + (size_t)kb * D_DIM;
    const unsigned short* vt_i = vtp + (size_t)(kb >> 5) * (D_DIM * 32);
    short8 kfh[2][2], kfl[2][2], vf[4];
#pragma unroll
    for (int nb = 0; nb < 2; ++nb)
#pragma unroll
      for (int kc = 0; kc < 2; ++kc) {
        kfh[nb][kc] = *(const short8*)(kh_i + nb * 16 * D_DIM + kc * 32);
        kfl[nb][kc] = *(const short8*)(kl_i + nb * 16 * D_DIM + kc * 32);
      }
#pragma unroll
    for (int n = 0; n < 4; ++n)
      vf[n] = *(const short8*)(vt_i + n * 16 * 32);

    // ---- PV for tile t-1 (P long since landed in Ph[cur]; MFMA pipe runs
    // in parallel with the threefry VALU block below)
    short8 pa = *(const short8*)(p_rd0 + cur * PBUF);
#pragma unroll
    for (int n = 0; n < 4; ++n)
      o_acc[n] = MFMA(pa, vf_prev[n], o_acc[n]);

    // ---- threefry tile t (covers the fragment-load latency)
    unsigned w[8];
#pragma unroll
    for (int r = 0; r < 4; ++r) {
      unsigned i0 = ibase0 + (unsigned)kb + (unsigned)(r * S_LEN);
      tf2(i0, i0 + 16u, w[r * 2], w[r * 2 + 1]);
    }

    // ---- S = Q K^T tile t (hh + hl + lh)
    floatx4 sc[2];
#pragma unroll
    for (int nb = 0; nb < 2; ++nb) {
      floatx4 acc = (floatx4){0.f, 0.f, 0.f, 0.f};
#pragma unroll
      for (int kc = 0; kc < 2; ++kc) {
        acc = MFMA(qh[kc], kfh[nb][kc], acc);
        acc = MFMA(qh[kc], kfl[nb][kc], acc);
        acc = MFMA(ql[kc], kfh[nb][kc], acc);
      }
      sc[nb] = acc;
    }

    // ---- exp/mask tile t -> Ph[cur^1] (consumed next iteration)
#pragma unroll
    for (int r = 0; r < 4; ++r)
#pragma unroll
      for (int nb = 0; nb < 2; ++nb) {
        float pe = __expf(sc[nb][r]);
        lsum[r] += pe;
        unsigned hbits = __float_as_uint(pe) >> 16;
        hbits = ((int)w[r * 2 + nb] < 0) ? 0u : hbits;
        p_wr0[(cur ^ 1) * PBUF + r * PSTR + nb * 16] = (unsigned short)hbits;
      }

#pragma unroll
    for (int n = 0; n < 4; ++n) vf_prev[n] = vf[n];
    cur ^= 1;
  }

  // ================= epilogue: PV for tile 63 =================
  {
    short8 pa = *(const short8*)(p_rd0 + cur * PBUF);
#pragma unroll
    for (int n = 0; n < 4; ++n)
      o_acc[n] = MFMA(pa, vf_prev[n], o_acc[n]);
  }

#pragma unroll
  for (int off = 8; off >= 1; off >>= 1)
#pragma unroll
    for (int r = 0; r < 4; ++r)
      lsum[r] += __shfl_xor(lsum[r], off, 64);

#pragma unroll
  for (int r = 0; r < 4; ++r) {
    float scale = 2.0f / lsum[r];
#pragma unroll
    for (int n = 0; n < 4; ++n) {
      Og[head_off + (size_t)(q0 + quad * 4 + r) * D_DIM + n * 16 + m16] =
          o_acc[n][r] * scale;
    }
  }
}

// ---- fallback monolith (verified v10, 770us): in-kernel split + LDS staging.
__global__ __launch_bounds__(256, 6) void attn_mono(
    const float* __restrict__ Qg, const float* __restrict__ Kg,
    const float* __restrict__ Vg, float* __restrict__ Og) {

  __shared__ __attribute__((aligned(16))) unsigned short Kh[KT * KSTR];
  __shared__ __attribute__((aligned(16))) unsigned short Kl[KT * KSTR];
  __shared__ __attribute__((aligned(16))) unsigned short Vs[KT * VROW];
  __shared__ __attribute__((aligned(16))) unsigned short Ps[NWAVE][QT * PSTR];

  const int tid  = threadIdx.x;
  const int wave = tid >> 6;
  const int lane = tid & 63;
  const int m16  = lane & 15;
  const int quad = lane >> 4;

  const int bh    = blockIdx.x >> 5;
  const int qtile = blockIdx.x & 31;
  const int q0    = qtile * (QT * NWAVE) + wave * QT;
  const size_t head_off = (size_t)bh * S_LEN * D_DIM;

  short8 qh[2], ql[2];
#pragma unroll
  for (int kc = 0; kc < 2; ++kc) {
    const float* qp = Qg + head_off + (size_t)(q0 + m16) * D_DIM + kc * 32 + quad * 8;
    floatx4 f0 = *(const floatx4*)qp;
    floatx4 f1 = *(const floatx4*)(qp + 4);
#pragma unroll
    for (int e = 0; e < 4; ++e) {
      unsigned short h, l;
      split_bf16(f0[e], h, l);
      qh[kc][e] = (short)h;  ql[kc][e] = (short)l;
      split_bf16(f1[e], h, l);
      qh[kc][4 + e] = (short)h;  ql[kc][4 + e] = (short)l;
    }
  }

  floatx4 o_acc[4];
#pragma unroll
  for (int n = 0; n < 4; ++n) o_acc[n] = (floatx4){0.f, 0.f, 0.f, 0.f};
  float lsum[4];
#pragma unroll
  for (int r = 0; r < 4; ++r) lsum[r] = 0.f;

  const unsigned ibase0 =
      ((unsigned)(bh * S_LEN + q0 + quad * 4)) * (unsigned)S_LEN + (unsigned)m16;

  for (int kb = 0; kb < S_LEN; kb += KT) {
    __syncthreads();
    for (int f = tid; f < KT * (D_DIM / 4); f += 256) {
      int row = f >> 4;
      int c4  = (f & 15) << 2;
      size_t goff = head_off + (size_t)(kb + row) * D_DIM + c4;
      floatx4 kv = *(const floatx4*)(Kg + goff);
      floatx4 vv = *(const floatx4*)(Vg + goff);
      unsigned short h0, h1, h2, h3, l0, l1, l2, l3;
      split_bf16(kv[0], h0, l0); split_bf16(kv[1], h1, l1);
      split_bf16(kv[2], h2, l2); split_bf16(kv[3], h3, l3);
      int kidx = row * KSTR + c4;
      *(unsigned*)&Kh[kidx]     = (unsigned)h0 | ((unsigned)h1 << 16);
      *(unsigned*)&Kh[kidx + 2] = (unsigned)h2 | ((unsigned)h3 << 16);
      *(unsigned*)&Kl[kidx]     = (unsigned)l0 | ((unsigned)l1 << 16);
      *(unsigned*)&Kl[kidx + 2] = (unsigned)l2 | ((unsigned)l3 << 16);
      unsigned v01 = (__float_as_uint(vv[0]) >> 16) |
                     (__float_as_uint(vv[1]) & 0xFFFF0000u);
      unsigned v23 = (__float_as_uint(vv[2]) >> 16) |
                     (__float_as_uint(vv[3]) & 0xFFFF0000u);
      int vidx = row * VROW + c4;
      *(unsigned*)&Vs[vidx]     = v01;
      *(unsigned*)&Vs[vidx + 2] = v23;
    }
    __syncthreads();

    floatx4 sc[2];
#pragma unroll
    for (int nb = 0; nb < 2; ++nb) {
      floatx4 acc = (floatx4){0.f, 0.f, 0.f, 0.f};
#pragma unroll
      for (int kc = 0; kc < 2; ++kc) {
        int bidx = (nb * 16 + m16) * KSTR + kc * 32 + quad * 8;
        short8 kbh = *(const short8*)&Kh[bidx];
        short8 kbl = *(const short8*)&Kl[bidx];
        acc = MFMA(qh[kc], kbh, acc);
        acc = MFMA(qh[kc], kbl, acc);
        acc = MFMA(ql[kc], kbh, acc);
      }
      sc[nb] = acc;
    }

#pragma unroll
    for (int r = 0; r < 4; ++r) {
      unsigned i0 = ibase0 + (unsigned)kb + (unsigned)(r * S_LEN);
      unsigned w0, w1;
      tf2(i0, i0 + 16u, w0, w1);
#pragma unroll
      for (int nb = 0; nb < 2; ++nb) {
        float pe = __expf(sc[nb][r]);
        lsum[r] += pe;
        unsigned hbits = __float_as_uint(pe) >> 16;
        unsigned w = nb ? w1 : w0;
        hbits = ((int)w < 0) ? 0u : hbits;
        Ps[wave][(quad * 4 + r) * PSTR + nb * 16 + m16] = (unsigned short)hbits;
      }
    }

    short8 pa = *(const short8*)&Ps[wave][m16 * PSTR + quad * 8];
#pragma unroll
    for (int n = 0; n < 4; ++n) {
      short8 vb;
#pragma unroll
      for (int j = 0; j < 8; ++j)
        vb[j] = (short)Vs[(quad * 8 + j) * VROW + n * 16 + m16];
      o_acc[n] = MFMA(pa, vb, o_acc[n]);
    }
  }

#pragma unroll
  for (int off = 8; off >= 1; off >>= 1)
#pragma unroll
    for (int r = 0; r < 4; ++r)
      lsum[r] += __shfl_xor(lsum[r], off, 64);

#pragma unroll
  for (int r = 0; r < 4; ++r) {
    float scale = 2.0f / lsum[r];
#pragma unroll
    for (int n = 0; n < 4; ++n) {
      Og[head_off + (size_t)(q0 + quad * 4 + r) * D_DIM + n * 16 + m16] =
          o_acc[n][r] * scale;
    }
  }
}

extern "C" void kernel_launch(void* const* d_in, const int* in_sizes, int n_in,
                              void* d_out, int out_size, void* d_ws, size_t ws_size,
                              hipStream_t stream) {
  (void)in_sizes; (void)n_in; (void)out_size;
  const float* Q = (const float*)d_in[0];
  const float* K = (const float*)d_in[1];
  const float* V = (const float*)d_in[2];
  float* O = (float*)d_out;

  const size_t KELTS = (size_t)64 * S_LEN * D_DIM;              // 8,388,608
  const size_t NEED  = 3 * KELTS * sizeof(unsigned short);      // 48 MiB
  if (d_ws != nullptr && ws_size >= NEED) {
    unsigned short* KH = (unsigned short*)d_ws;
    unsigned short* KL = KH + KELTS;
    unsigned short* VT = KL + KELTS;
    hipLaunchKernelGGL(prep_all, dim3(8192 + 4096), dim3(256), 0, stream,
                       K, V, KH, KL, VT);
    hipLaunchKernelGGL(attn_v14, dim3(2048), dim3(256), 0, stream, Q, O, KH, KL, VT);
  } else {
    hipLaunchKernelGGL(attn_mono, dim3(2048), dim3(256), 0, stream, Q, K, V, O);
  }
}